// Round 5
// baseline (4288.955 us; speedup 1.0000x reference)
//
#include <hip/hip_runtime.h>

#define T_STEPS 63
#define NWG 256
#define WG_SIZE 256
#define NA 32
#define NV 224
#define NJC 14   // vocab j-chunks (2304 words each); group = 16 consecutive vocab WGs
#define NDC 16   // d/gate-col chunks (32 d-cols / 128 gate-cols each)
#define NHM 15   // hflag mirrors: 14 jc groups + 1 for A-WGs

typedef float floatx4 __attribute__((ext_vector_type(4)));
typedef __bf16 bf16x8 __attribute__((ext_vector_type(8)));

__device__ __forceinline__ unsigned short f2bf(float x) {
  unsigned int u = __builtin_bit_cast(unsigned int, x);
  u += 0x7fffu + ((u >> 16) & 1u);
  return (unsigned short)(u >> 16);
}
__device__ __forceinline__ float sigmoidf(float x) {
  return 1.0f / (1.0f + __expf(-x));
}
__device__ __forceinline__ floatx4 mfma_bf16(bf16x8 a, bf16x8 b, floatx4 c) {
  return __builtin_amdgcn_mfma_f32_16x16x32_bf16(a, b, c, 0, 0, 0);
}
__device__ __forceinline__ floatx4 mfma_fp8(long a, long b, floatx4 c) {
  return __builtin_amdgcn_mfma_f32_16x16x32_fp8_fp8(a, b, c, 0, 0, 0);
}
__device__ __forceinline__ unsigned char f2fp8(float x) {
  return (unsigned char)(__builtin_amdgcn_cvt_pk_fp8_f32(x, x, 0, false) & 0xff);
}

// ---- device-scope (MALL) relaxed atomics ----
__device__ __forceinline__ unsigned long long ald64(const void* p) {
  return __hip_atomic_load((const unsigned long long*)p, __ATOMIC_RELAXED, __HIP_MEMORY_SCOPE_AGENT);
}
__device__ __forceinline__ float aldf(const float* p) {
  return __hip_atomic_load(p, __ATOMIC_RELAXED, __HIP_MEMORY_SCOPE_AGENT);
}
__device__ __forceinline__ void astf(float* p, float v) {
  __hip_atomic_store(p, v, __ATOMIC_RELAXED, __HIP_MEMORY_SCOPE_AGENT);
}
__device__ __forceinline__ void astu16(unsigned short* p, unsigned short v) {
  __hip_atomic_store(p, v, __ATOMIC_RELAXED, __HIP_MEMORY_SCOPE_AGENT);
}
__device__ __forceinline__ void astu32(unsigned int* p, unsigned int v) {
  __hip_atomic_store(p, v, __ATOMIC_RELAXED, __HIP_MEMORY_SCOPE_AGENT);
}
__device__ __forceinline__ void astu8(unsigned char* p, unsigned char v) {
  __hip_atomic_store(p, v, __ATOMIC_RELAXED, __HIP_MEMORY_SCOPE_AGENT);
}
__device__ __forceinline__ void afaddf(float* p, float v) {
  __hip_atomic_fetch_add(p, v, __ATOMIC_RELAXED, __HIP_MEMORY_SCOPE_AGENT);
}
__device__ __forceinline__ void afaddi(int* p, int v) {
  __hip_atomic_fetch_add(p, v, __ATOMIC_RELAXED, __HIP_MEMORY_SCOPE_AGENT);
}
__device__ __forceinline__ bf16x8 ld_bf8_at(const void* p) {
  union { unsigned long long q[2]; bf16x8 v; } u;
  u.q[0] = ald64(p);
  u.q[1] = ald64((const char*)p + 8);
  return u.v;
}

// busy-spin (no s_sleep: poll pace is self-limited by MALL load RTT)
__device__ __forceinline__ void spin_until(const int* f, int target) {
  while (__hip_atomic_load(f, __ATOMIC_RELAXED, __HIP_MEMORY_SCOPE_AGENT) < target) { }
}
__device__ __forceinline__ void signal_flag(int* f) {
  __builtin_amdgcn_s_waitcnt(0);
  __syncthreads();
  if (threadIdx.x == 0)
    __hip_atomic_fetch_add(f, 1, __ATOMIC_RELAXED, __HIP_MEMORY_SCOPE_AGENT);
}
__device__ __forceinline__ void wait_flag(const int* f, int target) {
  if (threadIdx.x == 0) spin_until(f, target);
  __syncthreads();
}

// ---- prologue: tiled transpose fp32 -> bf16 ----
__global__ void k_transpose(const float* __restrict__ in, unsigned short* __restrict__ out,
                            int R, int C, int ostride, int ooff) {
  __shared__ unsigned short tile[64][65];
  const int r0 = blockIdx.x << 6, c0 = blockIdx.y << 6;
  const int t = threadIdx.x;
  const int tr4 = t >> 6, tc = t & 63;
#pragma unroll
  for (int p = 0; p < 16; ++p) {
    int i = (p << 2) + tr4;
    int r = r0 + i;
    unsigned short v = 0;
    if (r < R) v = f2bf(in[(size_t)r * C + (c0 + tc)]);
    tile[i][tc] = v;
  }
  __syncthreads();
#pragma unroll
  for (int p = 0; p < 16; ++p) {
    int j = (p << 2) + tr4;
    int r = r0 + tc;
    if (r < R) out[(size_t)(c0 + j) * ostride + ooff + r] = tile[tc][j];
  }
}

// ---- prologue: tiled transpose fp32 -> fp8 with scale ----
__global__ void k_transpose_fp8(const float* __restrict__ in, unsigned char* __restrict__ out,
                                int R, int C, long OS, float scale) {
  __shared__ unsigned char tile[64][68];
  const int r0 = blockIdx.x << 6, c0 = blockIdx.y << 6;
  const int t = threadIdx.x;
  const int tr4 = t >> 6, tc = t & 63;
#pragma unroll
  for (int p = 0; p < 16; ++p) {
    int i = (p << 2) + tr4;
    int r = r0 + i;
    float v = (r < R) ? in[(size_t)r * C + (c0 + tc)] * scale : 0.f;
    tile[i][tc] = f2fp8(v);
  }
  __syncthreads();
#pragma unroll
  for (int p = 0; p < 16; ++p) {
    int j = (p << 2) + tr4;
    out[(size_t)(c0 + j) * OS + r0 + tc] = tile[tc][j];
  }
}

// ---- prologue: E8[32256][512] = fp8(E * 16), rows >= 32000 zero ----
__global__ void k_cast_e8(const float* __restrict__ E, unsigned char* __restrict__ E8) {
  const int stride = gridDim.x * blockDim.x;
  const int total = 32256 * 512 / 4;
  for (int i = blockIdx.x * blockDim.x + threadIdx.x; i < total; i += stride) {
    int row = i >> 7;                       // i*4/512
    unsigned int w = 0;
    if (row < 32000) {
      const float* p = E + (size_t)i * 4;
      int lo = __builtin_amdgcn_cvt_pk_fp8_f32(p[0] * 16.f, p[1] * 16.f, 0, false);
      w = (unsigned int)__builtin_amdgcn_cvt_pk_fp8_f32(p[2] * 16.f, p[3] * 16.f, lo, true);
    }
    *(unsigned int*)(E8 + (size_t)i * 4) = w;
  }
}

// ---- prologue: MT8[2048][32768] = fp8( (Wk8T x E8^T) * 0.5 )  == fp8(M^T * 128) ----
// M = E @ Wk_emb;  Wk8T = fp8(Wk_emb^T * 16), E8 = fp8(E * 16) -> product scale 256, *0.5 -> 128.
__global__ void __launch_bounds__(256) k_gemm_m(const unsigned char* __restrict__ Wk8T,
                                               const unsigned char* __restrict__ E8,
                                               unsigned char* __restrict__ MT8) {
  const int j0 = blockIdx.x << 7, g0 = blockIdx.y << 7;
  const int t = threadIdx.x, wv = t >> 6, lane = t & 63;
  const int q = lane >> 4, m16 = lane & 15;
  const int gtb = wv << 1;
  floatx4 acc[2][8];
#pragma unroll
  for (int a = 0; a < 2; ++a)
#pragma unroll
    for (int b = 0; b < 8; ++b) acc[a][b] = floatx4{0.f, 0.f, 0.f, 0.f};
#pragma unroll 4
  for (int ks = 0; ks < 16; ++ks) {
    long a0 = *(const long*)(Wk8T + (size_t)(g0 + gtb * 16 + m16) * 512 + ks * 32 + q * 8);
    long a1 = *(const long*)(Wk8T + (size_t)(g0 + gtb * 16 + 16 + m16) * 512 + ks * 32 + q * 8);
#pragma unroll
    for (int jt = 0; jt < 8; ++jt) {
      long b = *(const long*)(E8 + (size_t)(j0 + jt * 16 + m16) * 512 + ks * 32 + q * 8);
      acc[0][jt] = mfma_fp8(a0, b, acc[0][jt]);
      acc[1][jt] = mfma_fp8(a1, b, acc[1][jt]);
    }
  }
#pragma unroll
  for (int gt2 = 0; gt2 < 2; ++gt2)
#pragma unroll
    for (int jt = 0; jt < 8; ++jt)
#pragma unroll
      for (int r = 0; r < 4; ++r) {
        int g = g0 + (gtb + gt2) * 16 + (q << 2) + r;
        int j = j0 + jt * 16 + m16;
        MT8[(size_t)g * 32768 + j] = f2fp8(acc[gt2][jt][r] * 0.5f);
      }
}

// ---- prologue: cs_bf[32][160] = bf16(content|style|pad0); out[:,0,:] = E[0] ----
__global__ void k_init(const float* __restrict__ content, const float* __restrict__ style,
                       const float* __restrict__ E, unsigned short* cs_bf, float* out) {
  const int stride = gridDim.x * blockDim.x;
  const int idx = blockIdx.x * blockDim.x + threadIdx.x;
  for (int i = idx; i < 32 * 160; i += stride) {
    int b = i / 160, k = i - b * 160;
    float v = 0.f;
    if (k < 128)      v = content[b * 128 + k];
    else if (k < 144) v = style[b * 16 + (k - 128)];
    cs_bf[i] = f2bf(v);
  }
  for (int i = idx; i < 32 * 512; i += stride) {
    int b = i >> 9, d = i & 511;
    out[(size_t)b * (64 * 512) + d] = E[d];
  }
}

// LDS layout (byte offsets), per-WG role:
//  vocab WG (wg>=32): Ws8   @0       [144][512] fp8, 8B-group XOR-swizzled by (row&7)
//                     E8TS  @73728   [32][2304] fp8 slice, 8B-group rotated by row
//                     e_lds @147456  [32][160]  fp8
//  A WG (wg<32):      wkr   @0       [64][1192] bf16
//                     zbuf  @152576  [4][32][16] f32
#define SMEM_BYTES 160768
#define OFF_E8TS_L 73728
#define OFF_ELDS_L 147456
#define OFF_ZBUF_L 152576

__global__ void __launch_bounds__(WG_SIZE, 1) k_main(
    const float* __restrict__ bvec,          // [2048]
    const float* __restrict__ bs,            // [32000]
    const unsigned char* __restrict__ Ws8_g, // [32256][512] fp8 (Ws^T)
    const unsigned char* __restrict__ E8T_g, // [512][32768]  fp8 (E^T)
    const unsigned short* __restrict__ WkrT, // [2048][1184]  bf16
    const unsigned short* __restrict__ cs_bf,// [32][160] bf16
    const float* __restrict__ E,             // [32000][512] fp32 (row 0 at s=0)
    const unsigned char* __restrict__ MT8,   // [2048][32768] fp8 (M^T * 128)
    unsigned short* h_bufg,  // [32][512] bf16
    unsigned char* h8,       // [32][512] fp8
    unsigned char* e8g,      // [2][32][32768] fp8 (parity dbuf)
    float* Upart,            // [2][NDC][NJC][32][32] f32 (parity dbuf)
    float* Zp,               // [NJC][32][2048] f32 z-space partials
    float* Zbuf,             // [2][NJC][32] f32 softmax denominators (atomic)
    int* hflag, int* qflag, int* zflag, int* gflag, int* pvflag,
    float* out)
{
  const int wg = blockIdx.x;
  const int t  = threadIdx.x;
  const int wv = t >> 6;
  const int lane = t & 63;
  const int q = lane >> 4;
  const int m16 = lane & 15;

  __shared__ __align__(16) char smem[SMEM_BYTES];
  unsigned char* lds_ws   = (unsigned char*)smem;
  unsigned char* lds_e8ts = (unsigned char*)(smem + OFF_E8TS_L);
  unsigned char* lds_e    = (unsigned char*)(smem + OFF_ELDS_L);
  unsigned short* lds_wkr = (unsigned short*)smem;
  float* zbuf = (float*)(smem + OFF_ZBUF_L);

  if (wg < NA) {
    // ---------------- A-WG: LSTM owner of d-slice [wg*16, wg*16+16) ----------------
    for (int idx = t; idx < 64 * 148; idx += WG_SIZE) {
      int row = idx / 148, grp = idx - row * 148;
      int g = row >> 4, c = row & 15;
      int n = g * 512 + (wg << 4) + c;
      ulong2 v = *(const ulong2*)(WkrT + (size_t)n * 1184 + grp * 8);
      *(ulong2*)((char*)lds_wkr + row * 2384 + grp * 16) = v;
    }
    const int dl = t & 15;
    const float bias0 = bvec[0 * 512 + (wg << 4) + dl];
    const float bias1 = bvec[1 * 512 + (wg << 4) + dl];
    const float bias2 = bvec[2 * 512 + (wg << 4) + dl];
    const float bias3 = bvec[3 * 512 + (wg << 4) + dl];
    float c2[2] = {0.f, 0.f};
    __syncthreads();

    const int mt = wv & 1, g0w = (wv >> 1) << 1;
    const int row = mt * 16 + m16;
    const unsigned short* b0row = lds_wkr + (g0w * 16 + m16) * 1192;
    const unsigned short* b1row = lds_wkr + ((g0w + 1) * 16 + m16) * 1192;
    const int d = (wg << 4) + dl;
    const int dc_a = wg >> 1;                 // d-chunk (Upart) this slice lives in
    const int dl32 = ((wg & 1) << 4) + dl;    // col within the 32-wide d-chunk
    const int gcbase = wg >> 3;               // gate-col-chunk base (0..3)

    floatx4 accG0 = {0.f, 0.f, 0.f, 0.f}, accG1 = {0.f, 0.f, 0.f, 0.f};
    float inv[2] = {0.f, 0.f};
    float zr[2][4];

    for (int s = 0; s < T_STEPS; ++s) {
      if (s == 0) {
        // cs-part
#pragma unroll
        for (int ks = 16; ks < 21; ++ks) {
          bf16x8 a = *(const bf16x8*)(cs_bf + row * 160 + (ks - 16) * 32 + q * 8);
          accG0 = mfma_bf16(a, *(const bf16x8*)(b0row + ks * 32 + q * 8), accG0);
          accG1 = mfma_bf16(a, *(const bf16x8*)(b1row + ks * 32 + q * 8), accG1);
        }
        // emb from E row 0
#pragma unroll 4
        for (int ks = 0; ks < 16; ++ks) {
          const float* ep = E + ks * 32 + q * 8;
          bf16x8 a;
#pragma unroll
          for (int i = 0; i < 8; ++i) a[i] = (__bf16)ep[i];
          accG0 = mfma_bf16(a, *(const bf16x8*)(b0row + ks * 32 + q * 8), accG0);
          accG1 = mfma_bf16(a, *(const bf16x8*)(b1row + ks * 32 + q * 8), accG1);
        }
      } else {
        // wait z-partials of step s-1 (4 gate-col chunks) + precompute-done of s-1
        if (t < 4) spin_until(zflag + (((s - 1) * NDC + (t * 4 + gcbase)) << 4), NJC);
        else if (t == 4) spin_until(gflag + ((s - 1) << 4), NA);
        __syncthreads();
        const int pc1 = (s - 1) & 1;
        // z-reduce: zr[pp][gate] = (sum_jc Zp) / (128*Z)
#pragma unroll
        for (int pp = 0; pp < 2; ++pp) {
          const int b = (pp * 256 + t) >> 4;
          const float* zp = Zp + (size_t)b * 2048 + (wg << 4) + dl;
          float z0 = 0.f, z1 = 0.f, z2 = 0.f, z3 = 0.f, Zv = 0.f;
#pragma unroll
          for (int jc = 0; jc < NJC; ++jc) {
            const float* p = zp + jc * 65536;
            z0 += aldf(p);
            z1 += aldf(p + 512);
            z2 += aldf(p + 1024);
            z3 += aldf(p + 1536);
            Zv += aldf(Zbuf + pc1 * (NJC * 32) + jc * 32 + b);
          }
          float iv = 1.0f / (128.0f * Zv);
          inv[pp] = iv;
          zr[pp][0] = z0 * iv; zr[pp][1] = z1 * iv;
          zr[pp][2] = z2 * iv; zr[pp][3] = z3 * iv;
        }
      }
      // --- exchange z (h+cs part) via LDS ---
#pragma unroll
      for (int r = 0; r < 4; ++r) {
        zbuf[(g0w * 32 + mt * 16 + q * 4 + r) * 16 + m16] = accG0[r];
        zbuf[((g0w + 1) * 32 + mt * 16 + q * 4 + r) * 16 + m16] = accG1[r];
      }
      __syncthreads();
      // --- LSTM pointwise; stage h ---
#pragma unroll
      for (int pp = 0; pp < 2; ++pp) {
        const int b = (pp * 256 + t) >> 4;
        float zi = zbuf[(0 * 32 + b) * 16 + dl] + bias0;
        float zf = zbuf[(1 * 32 + b) * 16 + dl] + bias1;
        float zg = zbuf[(2 * 32 + b) * 16 + dl] + bias2;
        float zo = zbuf[(3 * 32 + b) * 16 + dl] + bias3;
        if (s > 0) { zi += zr[pp][0]; zf += zr[pp][1]; zg += zr[pp][2]; zo += zr[pp][3]; }
        float iv = sigmoidf(zi), fv = sigmoidf(zf);
        float gv = tanhf(zg),    ov = sigmoidf(zo);
        c2[pp] = fv * c2[pp] + iv * gv;
        float h = ov * tanhf(c2[pp]);
        astu16(h_bufg + b * 512 + d, f2bf(h));
        astu8(h8 + b * 512 + d, f2fp8(h));
      }
      // --- signal h ready to all mirrors ---
      __builtin_amdgcn_s_waitcnt(0);
      __syncthreads();
      if (t < NHM) afaddi(hflag + ((s * NHM + t) << 4), 1);
      // --- precompute h+cs part of z(s+1) (overlaps V stage); gflag makes it structural ---
      if (s + 1 < T_STEPS) {
        wait_flag(hflag + ((s * NHM + (NHM - 1)) << 4), NA);
        accG0 = floatx4{0.f, 0.f, 0.f, 0.f};
        accG1 = floatx4{0.f, 0.f, 0.f, 0.f};
#pragma unroll 8
        for (int ks = 21; ks < 37; ++ks) {
          bf16x8 a = ld_bf8_at(h_bufg + row * 512 + (ks - 21) * 32 + q * 8);
          accG0 = mfma_bf16(a, *(const bf16x8*)(b0row + ks * 32 + q * 8), accG0);
          accG1 = mfma_bf16(a, *(const bf16x8*)(b1row + ks * 32 + q * 8), accG1);
        }
#pragma unroll
        for (int ks = 16; ks < 21; ++ks) {
          bf16x8 a = *(const bf16x8*)(cs_bf + row * 160 + (ks - 16) * 32 + q * 8);
          accG0 = mfma_bf16(a, *(const bf16x8*)(b0row + ks * 32 + q * 8), accG0);
          accG1 = mfma_bf16(a, *(const bf16x8*)(b1row + ks * 32 + q * 8), accG1);
        }
        signal_flag(gflag + (s << 4));
      }
      // --- off-chain: out[:, s] from Upart(s-1); zero consumed Z parity ---
      if (s >= 1) {
        wait_flag(pvflag + (((s - 1) * NDC + dc_a) << 4), NJC);
        const int pc1 = (s - 1) & 1;
#pragma unroll
        for (int pp = 0; pp < 2; ++pp) {
          const int b = (pp * 256 + t) >> 4;
          float uv = 0.f;
          const float* up = Upart + (size_t)pc1 * 229376 + ((size_t)(dc_a * NJC) * 32 + b) * 32 + dl32;
#pragma unroll
          for (int jc = 0; jc < NJC; ++jc) uv += aldf(up + jc * 1024);
          out[(size_t)b * (64 * 512) + (size_t)s * 512 + d] = uv * inv[pp] * 128.0f;
        }
        if (t < NJC) astf(Zbuf + pc1 * (NJC * 32) + t * 32 + wg, 0.0f);
      }
    }
    // --- epilogue: out[:, 63] from Upart(62) ---
    {
      wait_flag(pvflag + (((T_STEPS - 1) * NDC + dc_a) << 4), NJC);
      const int pc1 = (T_STEPS - 1) & 1;   // 0
#pragma unroll
      for (int pp = 0; pp < 2; ++pp) {
        const int b = (pp * 256 + t) >> 4;
        float uv = 0.f, Zv = 0.f;
        const float* up = Upart + (size_t)pc1 * 229376 + ((size_t)(dc_a * NJC) * 32 + b) * 32 + dl32;
#pragma unroll
        for (int jc = 0; jc < NJC; ++jc) {
          uv += aldf(up + jc * 1024);
          Zv += aldf(Zbuf + pc1 * (NJC * 32) + jc * 32 + b);
        }
        out[(size_t)b * (64 * 512) + (size_t)T_STEPS * 512 + d] = uv / Zv;
      }
    }
  } else {
    // ---------------- vocab WG ----------------
    const int wgv = wg - NA;
    const int jc = wgv >> 4;          // j-chunk (2304 words)
    const int gc = wgv & 15;          // gate-col chunk (128) == d-chunk (32)
    const long j0 = (long)wgv * 144;  // own 144-word logits slice
    // Ws^T slice -> LDS
    for (int idx = t; idx < 144 * 64; idx += WG_SIZE) {
      int r2 = idx >> 6, grp = idx & 63;
      long v = *(const long*)(Ws8_g + (j0 + r2) * 512 + grp * 8);
      *(long*)(lds_ws + r2 * 512 + ((grp ^ (r2 & 7)) << 3)) = v;
    }
    // E^T slice [32 d][2304 j] -> LDS, rotated by d-row
    for (int idx = t; idx < 32 * 288; idx += WG_SIZE) {
      int dd = idx / 288, g = idx - dd * 288;
      long v = *(const long*)(E8T_g + (size_t)(gc * 32 + dd) * 32768 + (size_t)jc * 2304 + (size_t)g * 8);
      int g2 = g + dd; if (g2 >= 288) g2 -= 288;
      *(long*)(lds_e8ts + dd * 2304 + (g2 << 3)) = v;
    }
    __syncthreads();

    for (int s = 0; s < T_STEPS; ++s) {
      wait_flag(hflag + ((s * NHM + jc) << 4), NA);
      const int pc = s & 1;
      unsigned char* e8p = e8g + (size_t)pc * 1048576;
      long ah[2][16];
#pragma unroll
      for (int mtl = 0; mtl < 2; ++mtl)
#pragma unroll
        for (int ks = 0; ks < 16; ++ks)
          ah[mtl][ks] = (long)ald64(h8 + (mtl * 16 + m16) * 512 + ks * 32 + q * 8);
      // logits: 9 n-tiles round-robin over waves
      for (int tile = wv; tile < 9; tile += 4) {
        const int jl = tile * 16 + m16;
        const unsigned char* wrow = lds_ws + jl * 512;
        const int sw = jl & 7;
        floatx4 acc[2] = {{0,0,0,0},{0,0,0,0}};
#pragma unroll
        for (int ks = 0; ks < 16; ++ks) {
          int g = ks * 4 + q;
          long bfrag = *(const long*)(wrow + ((g ^ sw) << 3));
          acc[0] = mfma_fp8(ah[0][ks], bfrag, acc[0]);
          acc[1] = mfma_fp8(ah[1][ks], bfrag, acc[1]);
        }
        const long jg = j0 + jl;
        const float bsv = bs[jg < 32000 ? jg : 31999];
        const bool valid = (jg < 32000);
#pragma unroll
        for (int mtl = 0; mtl < 2; ++mtl)
#pragma unroll
          for (int r = 0; r < 4; ++r) {
            float e = valid ? __expf(acc[mtl][r] + bsv) : 0.0f;
            lds_e[(mtl * 16 + q * 4 + r) * 160 + jl] = f2fp8(e);
          }
      }
      __syncthreads();
      // publish e slice (parity buffer)
      for (int idx = t; idx < 32 * 36; idx += WG_SIZE) {
        int b = idx / 36, g = idx - b * 36;
        unsigned int v = *(const unsigned int*)(lds_e + b * 160 + g * 4);
        astu32((unsigned int*)(e8p + (size_t)b * 32768 + j0 + g * 4), v);
      }
      signal_flag(qflag + ((s * NJC + jc) << 4));
      wait_flag(qflag + ((s * NJC + jc) << 4), 16);
      // Z partial (after qflag: off the exchange path; drained by zflag/pvflag signal)
      if (t >= 192 && t < 224) {
        const int b = t - 192;
        const unsigned int* rowp = (const unsigned int*)(lds_e + b * 160);
        float z = 0.f;
        for (int g = 0; g < 36; ++g) {
          int w4 = (int)rowp[g];
          z += __builtin_amdgcn_cvt_f32_fp8(w4, 0) + __builtin_amdgcn_cvt_f32_fp8(w4, 1)
             + __builtin_amdgcn_cvt_f32_fp8(w4, 2) + __builtin_amdgcn_cvt_f32_fp8(w4, 3);
        }
        afaddf(Zbuf + pc * (NJC * 32) + jc * 32 + b, z);
      }
      // --- zpart: Zp[jc][:, gc*128..+128] = e[:, jc-chunk] @ M^T-slice (CRITICAL) ---
      if (s < T_STEPS - 1) {
        const int mtp = wv & 1, ggb = (wv >> 1) << 2;
        const unsigned char* ab = e8p + (size_t)(mtp * 16 + m16) * 32768 + (size_t)jc * 2304;
        const unsigned char* mb = MT8 + (size_t)(gc * 128 + ggb * 16 + m16) * 32768 + (size_t)jc * 2304;
        floatx4 za0 = {0,0,0,0}, za1 = {0,0,0,0}, za2 = {0,0,0,0}, za3 = {0,0,0,0};
#pragma unroll 4
        for (int ks = 0; ks < 72; ++ks) {
          long a = (long)ald64(ab + ks * 32 + q * 8);
          long b0 = *(const long*)(mb + 0ull * 524288 + ks * 32 + q * 8);
          long b1 = *(const long*)(mb + 1ull * 524288 + ks * 32 + q * 8);
          long b2 = *(const long*)(mb + 2ull * 524288 + ks * 32 + q * 8);
          long b3 = *(const long*)(mb + 3ull * 524288 + ks * 32 + q * 8);
          za0 = mfma_fp8(a, b0, za0); za1 = mfma_fp8(a, b1, za1);
          za2 = mfma_fp8(a, b2, za2); za3 = mfma_fp8(a, b3, za3);
        }
        const int brow = mtp * 16 + (q << 2);
#pragma unroll
        for (int r = 0; r < 4; ++r) {
          float* zp = Zp + (size_t)(jc * 32 + brow + r) * 2048 + gc * 128 + ggb * 16 + m16;
          astf(zp +  0, za0[r]); astf(zp + 16, za1[r]);
          astf(zp + 32, za2[r]); astf(zp + 48, za3[r]);
        }
        signal_flag(zflag + ((s * NDC + gc) << 4));
      }
      // --- Upart PV for out (off-chain): u-partial [32 b][32 d of chunk gc] ---
      {
        const int mtp = wv & 1, ntl = wv >> 1;
        const int dl_local = ntl * 16 + m16;
        const unsigned char* erow = lds_e8ts + dl_local * 2304;
        const unsigned char* arow = e8p + (size_t)(mtp * 16 + m16) * 32768 + (size_t)jc * 2304;
        floatx4 acc0 = {0,0,0,0}, acc1 = {0,0,0,0};
#pragma unroll 8
        for (int ks = 0; ks < 72; ks += 2) {
          long a0 = (long)ald64(arow + ks * 32 + q * 8);
          long a1 = (long)ald64(arow + (ks + 1) * 32 + q * 8);
          int g0i = ks * 4 + q + dl_local; if (g0i >= 288) g0i -= 288;
          int g1i = g0i + 4;               if (g1i >= 288) g1i -= 288;
          acc0 = mfma_fp8(a0, *(const long*)(erow + (g0i << 3)), acc0);
          acc1 = mfma_fp8(a1, *(const long*)(erow + (g1i << 3)), acc1);
        }
        floatx4 accs = acc0 + acc1;
#pragma unroll
        for (int r = 0; r < 4; ++r)
          astf(Upart + (size_t)pc * 229376 +
               ((size_t)(gc * NJC + jc) * 32 + (mtp * 16 + (q << 2) + r)) * 32 + dl_local, accs[r]);
      }
      signal_flag(pvflag + ((s * NDC + gc) << 4));
    }
  }
}

// ---------------- host ----------------
extern "C" void kernel_launch(void* const* d_in, const int* in_sizes, int n_in,
                              void* d_out, int out_size, void* d_ws, size_t ws_size,
                              hipStream_t stream) {
  const float* content = (const float*)d_in[0];
  const float* style   = (const float*)d_in[1];
  const float* E       = (const float*)d_in[2];
  const float* Wk      = (const float*)d_in[3];
  const float* Wr      = (const float*)d_in[4];
  const float* bvec    = (const float*)d_in[5];
  const float* Ws      = (const float*)d_in[6];
  const float* bs      = (const float*)d_in[7];
  float* out = (float*)d_out;
  char* ws = (char*)d_ws;

  constexpr size_t SZ_WS8  = 32256ull * 512;             // 16,515,072
  constexpr size_t SZ_E8T  = 512ull * 32768;             // 16,777,216
  constexpr size_t SZ_WKRT = 2048ull * 1184 * 2;         //  4,849,664
  constexpr size_t SZ_CS   = 32ull * 160 * 2;            //     10,240
  constexpr size_t SZ_HB   = 32ull * 512 * 2;            //     32,768
  constexpr size_t SZ_H8   = 32ull * 512;                //     16,384
  constexpr size_t SZ_ZB   = 2ull * NJC * 32 * 4;        //      3,584
  constexpr size_t SZ_HF   = 63ull * NHM * 16 * 4;       //     60,480
  constexpr size_t SZ_QF   = 63ull * NJC * 16 * 4;       //     56,448
  constexpr size_t SZ_ZF   = 63ull * NDC * 16 * 4;       //     64,512
  constexpr size_t SZ_GF   = 63ull * 16 * 4;             //      4,032
  constexpr size_t SZ_PF   = 63ull * NDC * 16 * 4;       //     64,512
  constexpr size_t SZ_E8   = 32256ull * 512;             // 16,515,072 (prologue-only; k_main aliases)
  constexpr size_t SZ_WK8T = 2048ull * 512;              //  1,048,576
  constexpr size_t SZ_MT8  = 2048ull * 32768;            // 67,108,864

  constexpr size_t OFF_WS8  = 0;
  constexpr size_t OFF_E8T  = OFF_WS8 + SZ_WS8;
  constexpr size_t OFF_WKRT = OFF_E8T + SZ_E8T;
  constexpr size_t OFF_CS   = OFF_WKRT + SZ_WKRT;
  constexpr size_t OFF_HB   = OFF_CS + SZ_CS;
  constexpr size_t OFF_H8   = OFF_HB + SZ_HB;
  constexpr size_t OFF_ZB   = OFF_H8 + SZ_H8;
  constexpr size_t OFF_HFL  = OFF_ZB + SZ_ZB;
  constexpr size_t OFF_QFL  = OFF_HFL + SZ_HF;
  constexpr size_t OFF_ZFL  = OFF_QFL + SZ_QF;
  constexpr size_t OFF_GFL  = OFF_ZFL + SZ_ZF;
  constexpr size_t OFF_PFL  = OFF_GFL + SZ_GF;
  constexpr size_t OFF_E8   = OFF_PFL + SZ_PF;
  // k_main runtime buffers alias the (prologue-only) E8 region:
  constexpr size_t OFF_E8G  = OFF_E8;                    // 2,097,152
  constexpr size_t OFF_UP   = OFF_E8 + 2097152;          // 1,835,008
  constexpr size_t OFF_ZP   = OFF_E8 + 3932160;          // 3,670,016  (7,602,176 <= SZ_E8)
  constexpr size_t OFF_WK8T = OFF_E8 + SZ_E8;
  constexpr size_t OFF_MT8  = OFF_WK8T + SZ_WK8T;        // end ~123.1 MB

  unsigned char*  Ws8_g = (unsigned char*)(ws + OFF_WS8);
  unsigned char*  E8T_g = (unsigned char*)(ws + OFF_E8T);
  unsigned short* WkrT  = (unsigned short*)(ws + OFF_WKRT);
  unsigned short* cs_bf = (unsigned short*)(ws + OFF_CS);
  unsigned short* h_bufg= (unsigned short*)(ws + OFF_HB);
  unsigned char*  h8    = (unsigned char*)(ws + OFF_H8);
  float* Zbuf           = (float*)(ws + OFF_ZB);
  int* hflag            = (int*)(ws + OFF_HFL);
  int* qflag            = (int*)(ws + OFF_QFL);
  int* zflag            = (int*)(ws + OFF_ZFL);
  int* gflag            = (int*)(ws + OFF_GFL);
  int* pvflag           = (int*)(ws + OFF_PFL);
  unsigned char*  E8    = (unsigned char*)(ws + OFF_E8);
  unsigned char*  e8g   = (unsigned char*)(ws + OFF_E8G);
  float* Upart          = (float*)(ws + OFF_UP);
  float* Zp             = (float*)(ws + OFF_ZP);
  unsigned char*  Wk8T  = (unsigned char*)(ws + OFF_WK8T);
  unsigned char*  MT8   = (unsigned char*)(ws + OFF_MT8);

  // zero state (ws poisoned each call)
  hipMemsetAsync(Ws8_g, 0, SZ_WS8, stream);
  hipMemsetAsync(E8T_g, 0, SZ_E8T, stream);
  hipMemsetAsync(WkrT, 0, SZ_WKRT, stream);
  hipMemsetAsync(ws + OFF_ZB, 0, SZ_ZB + SZ_HF + SZ_QF + SZ_ZF + SZ_GF + SZ_PF, stream);

  // prologue: transposes / casts / M-GEMM
  k_transpose_fp8<<<dim3(8, 500), 256, 0, stream>>>(Ws, Ws8_g, 512, 32000, 512, 1.0f);
  k_transpose_fp8<<<dim3(500, 8), 256, 0, stream>>>(E, E8T_g, 32000, 512, 32768, 1.0f);
  k_transpose_fp8<<<dim3(8, 32), 256, 0, stream>>>(Wk, Wk8T, 512, 2048, 512, 16.0f);
  k_cast_e8<<<2048, 256, 0, stream>>>(E, E8);
  k_gemm_m<<<dim3(252, 16), 256, 0, stream>>>(Wk8T, E8, MT8);
  k_transpose<<<dim3(11, 32), 256, 0, stream>>>(Wk, WkrT, 656, 2048, 1184, 0);
  k_transpose<<<dim3(8, 32), 256, 0, stream>>>(Wr, WkrT, 512, 2048, 1184, 672);
  k_init<<<64, 256, 0, stream>>>(content, style, E, cs_bf, out);

  void* args[] = { (void*)&bvec, (void*)&bs, (void*)&Ws8_g, (void*)&E8T_g, (void*)&WkrT,
                   (void*)&cs_bf, (void*)&E, (void*)&MT8, (void*)&h_bufg, (void*)&h8,
                   (void*)&e8g, (void*)&Upart, (void*)&Zp, (void*)&Zbuf,
                   (void*)&hflag, (void*)&qflag, (void*)&zflag, (void*)&gflag, (void*)&pvflag,
                   (void*)&out };
  hipLaunchCooperativeKernel((void*)k_main, dim3(NWG), dim3(WG_SIZE), args, 0, stream);

  (void)in_sizes; (void)n_in; (void)out_size; (void)ws_size;
}

// Round 6
// 2073.017 us; speedup vs baseline: 2.0689x; 2.0689x over previous
//
#include <hip/hip_runtime.h>

#define T_STEPS 63
#define NWG 256
#define WG_SIZE 256
#define NA 32
#define NV 224
#define NJC 14   // vocab j-chunks (2304 words each); group = 16 consecutive vocab WGs
#define NDC 16   // d-chunks (32 cols each)

typedef float floatx4 __attribute__((ext_vector_type(4)));
typedef __bf16 bf16x8 __attribute__((ext_vector_type(8)));

__device__ __forceinline__ unsigned short f2bf(float x) {
  unsigned int u = __builtin_bit_cast(unsigned int, x);
  u += 0x7fffu + ((u >> 16) & 1u);
  return (unsigned short)(u >> 16);
}
__device__ __forceinline__ float sigmoidf(float x) {
  return 1.0f / (1.0f + __expf(-x));
}
__device__ __forceinline__ floatx4 mfma_bf16(bf16x8 a, bf16x8 b, floatx4 c) {
  return __builtin_amdgcn_mfma_f32_16x16x32_bf16(a, b, c, 0, 0, 0);
}
__device__ __forceinline__ floatx4 mfma_fp8(long a, long b, floatx4 c) {
  return __builtin_amdgcn_mfma_f32_16x16x32_fp8_fp8(a, b, c, 0, 0, 0);
}
__device__ __forceinline__ unsigned char f2fp8(float x) {
  return (unsigned char)(__builtin_amdgcn_cvt_pk_fp8_f32(x, x, 0, false) & 0xff);
}

// ---- device-scope (MALL) relaxed atomics ----
__device__ __forceinline__ unsigned long long ald64(const void* p) {
  return __hip_atomic_load((const unsigned long long*)p, __ATOMIC_RELAXED, __HIP_MEMORY_SCOPE_AGENT);
}
__device__ __forceinline__ float aldf(const float* p) {
  return __hip_atomic_load(p, __ATOMIC_RELAXED, __HIP_MEMORY_SCOPE_AGENT);
}
__device__ __forceinline__ int aldi(const int* p) {
  return __hip_atomic_load(p, __ATOMIC_RELAXED, __HIP_MEMORY_SCOPE_AGENT);
}
__device__ __forceinline__ void astf(float* p, float v) {
  __hip_atomic_store(p, v, __ATOMIC_RELAXED, __HIP_MEMORY_SCOPE_AGENT);
}
__device__ __forceinline__ void asti(int* p, int v) {
  __hip_atomic_store(p, v, __ATOMIC_RELAXED, __HIP_MEMORY_SCOPE_AGENT);
}
__device__ __forceinline__ void astu16(unsigned short* p, unsigned short v) {
  __hip_atomic_store(p, v, __ATOMIC_RELAXED, __HIP_MEMORY_SCOPE_AGENT);
}
__device__ __forceinline__ void astu32(unsigned int* p, unsigned int v) {
  __hip_atomic_store(p, v, __ATOMIC_RELAXED, __HIP_MEMORY_SCOPE_AGENT);
}
__device__ __forceinline__ void astu8(unsigned char* p, unsigned char v) {
  __hip_atomic_store(p, v, __ATOMIC_RELAXED, __HIP_MEMORY_SCOPE_AGENT);
}
__device__ __forceinline__ void afaddf(float* p, float v) {
  __hip_atomic_fetch_add(p, v, __ATOMIC_RELAXED, __HIP_MEMORY_SCOPE_AGENT);
}
__device__ __forceinline__ bf16x8 ld_bf8_at(const void* p) {
  union { unsigned long long q[2]; bf16x8 v; } u;
  u.q[0] = ald64(p);
  u.q[1] = ald64((const char*)p + 8);
  return u.v;
}

// wave-parallel stamp check: lane i polls stamp[i] (i<n); whole wave proceeds when
// all n stamps >= tgt. One parallel MALL RTT per poll round; zero RMW, zero sync.
__device__ __forceinline__ void wave_spin(const int* base, int n, int tgt) {
  const int lane = threadIdx.x & 63;
  int v;
  do {
    v = (lane < n) ? aldi(base + lane) : 0x7fffffff;
  } while (__any(v < tgt));
}
// drain own vmem, then publish own stamp slot (plain store, single writer)
__device__ __forceinline__ void stamp_publish(int* slot, int v) {
  __builtin_amdgcn_s_waitcnt(0);
  __syncthreads();
  if (threadIdx.x == 0) asti(slot, v);
}

// ---- prologue: tiled transpose fp32 -> bf16 ----
__global__ void k_transpose(const float* __restrict__ in, unsigned short* __restrict__ out,
                            int R, int C, int ostride, int ooff) {
  __shared__ unsigned short tile[64][65];
  const int r0 = blockIdx.x << 6, c0 = blockIdx.y << 6;
  const int t = threadIdx.x;
  const int tr4 = t >> 6, tc = t & 63;
#pragma unroll
  for (int p = 0; p < 16; ++p) {
    int i = (p << 2) + tr4;
    int r = r0 + i;
    unsigned short v = 0;
    if (r < R) v = f2bf(in[(size_t)r * C + (c0 + tc)]);
    tile[i][tc] = v;
  }
  __syncthreads();
#pragma unroll
  for (int p = 0; p < 16; ++p) {
    int j = (p << 2) + tr4;
    int r = r0 + tc;
    if (r < R) out[(size_t)(c0 + j) * ostride + ooff + r] = tile[tc][j];
  }
}

// ---- prologue: tiled transpose fp32 -> fp8 ----
__global__ void k_transpose_fp8(const float* __restrict__ in, unsigned char* __restrict__ out,
                                int R, int C, long OS) {
  __shared__ unsigned char tile[64][68];
  const int r0 = blockIdx.x << 6, c0 = blockIdx.y << 6;
  const int t = threadIdx.x;
  const int tr4 = t >> 6, tc = t & 63;
#pragma unroll
  for (int p = 0; p < 16; ++p) {
    int i = (p << 2) + tr4;
    int r = r0 + i;
    float v = (r < R) ? in[(size_t)r * C + (c0 + tc)] : 0.f;
    tile[i][tc] = f2fp8(v);
  }
  __syncthreads();
#pragma unroll
  for (int p = 0; p < 16; ++p) {
    int j = (p << 2) + tr4;
    out[(size_t)(c0 + j) * OS + r0 + tc] = tile[tc][j];
  }
}

// ---- prologue: cs_bf[32][160] = bf16(content|style|pad0); out[:,0,:] = E[0] ----
__global__ void k_init(const float* __restrict__ content, const float* __restrict__ style,
                       const float* __restrict__ E, unsigned short* cs_bf, float* out) {
  const int stride = gridDim.x * blockDim.x;
  const int idx = blockIdx.x * blockDim.x + threadIdx.x;
  for (int i = idx; i < 32 * 160; i += stride) {
    int b = i / 160, k = i - b * 160;
    float v = 0.f;
    if (k < 128)      v = content[b * 128 + k];
    else if (k < 144) v = style[b * 16 + (k - 128)];
    cs_bf[i] = f2bf(v);
  }
  for (int i = idx; i < 32 * 512; i += stride) {
    int b = i >> 9, d = i & 511;
    out[(size_t)b * (64 * 512) + d] = E[d];
  }
}

// LDS layout (byte offsets), per-WG role:
//  vocab WG (wg>=32): Ws8   @0       [144][512] fp8, 8B-group XOR-swizzled by (row&7)
//                     E8TS  @73728   [32][2304] fp8 slice, 8B-group rotated by row
//                     e_lds @147456  [32][160]  fp8
//  A WG (wg<32):      wkr   @0       [64][1192] bf16
//                     zbuf  @152576  [4][32][16] f32
#define SMEM_BYTES 160768
#define OFF_E8TS_L 73728
#define OFF_ELDS_L 147456
#define OFF_ZBUF_L 152576

__global__ void __launch_bounds__(WG_SIZE, 1) k_main(
    const float* __restrict__ bvec,          // [2048]
    const float* __restrict__ bs,            // [32000]
    const unsigned char* __restrict__ Ws8_g, // [32256][512] fp8 (Ws^T)
    const unsigned char* __restrict__ E8T_g, // [512][32768]  fp8 (E^T)
    const unsigned short* __restrict__ WkrT, // [2048][1184]  bf16
    const unsigned short* __restrict__ cs_bf,// [32][160] bf16
    const float* __restrict__ E,             // [32000][512] fp32 (row 0 at s=0)
    unsigned short* h_bufg,  // [32][512] bf16
    unsigned char* h8,       // [32][512] fp8
    unsigned short* emb_bf,  // [32][512] bf16 normalized soft embedding
    unsigned char* e8g,      // [32][32768] fp8 e (softmax numerator)
    float* Upart,            // [NDC][NJC][32][32] f32 PV partials (plain stores)
    float* Zbuf,             // [2][NJC][32] f32 denominators (atomic, parity)
    int* hstep,              // [32]  A-WG w: h(s) published  -> s+1
    int* estep,              // [32]  A-WG w: emb(s) published -> s+1
    int* qstep,              // [NJC*16] vocab WG: e-slice(s) published -> s+1
    int* pvstep,             // [NDC][16] (jc slot 0..13): Upart(s) published -> s+1
    float* out)
{
  const int wg = blockIdx.x;
  const int t  = threadIdx.x;
  const int wv = t >> 6;
  const int lane = t & 63;
  const int q = lane >> 4;
  const int m16 = lane & 15;

  __shared__ __align__(16) char smem[SMEM_BYTES];
  unsigned char* lds_ws   = (unsigned char*)smem;
  unsigned char* lds_e8ts = (unsigned char*)(smem + OFF_E8TS_L);
  unsigned char* lds_e    = (unsigned char*)(smem + OFF_ELDS_L);
  unsigned short* lds_wkr = (unsigned short*)smem;
  float* zbuf = (float*)(smem + OFF_ZBUF_L);

  if (wg < NA) {
    // ---------------- A-WG: LSTM owner of d-slice [wg*16, wg*16+16) ----------------
    for (int idx = t; idx < 64 * 148; idx += WG_SIZE) {
      int row = idx / 148, grp = idx - row * 148;
      int g = row >> 4, c = row & 15;
      int n = g * 512 + (wg << 4) + c;
      ulong2 v = *(const ulong2*)(WkrT + (size_t)n * 1184 + grp * 8);
      *(ulong2*)((char*)lds_wkr + row * 2384 + grp * 16) = v;
    }
    const int dl = t & 15;
    const float bias0 = bvec[0 * 512 + (wg << 4) + dl];
    const float bias1 = bvec[1 * 512 + (wg << 4) + dl];
    const float bias2 = bvec[2 * 512 + (wg << 4) + dl];
    const float bias3 = bvec[3 * 512 + (wg << 4) + dl];
    float c2[2] = {0.f, 0.f};
    __syncthreads();

    const int mt = wv & 1, g0w = (wv >> 1) << 1;
    const int row = mt * 16 + m16;
    const unsigned short* b0row = lds_wkr + (g0w * 16 + m16) * 1192;
    const unsigned short* b1row = lds_wkr + ((g0w + 1) * 16 + m16) * 1192;
    const int d = (wg << 4) + dl;
    const int dc_a = wg >> 1;                 // d-chunk this slice lives in
    const int dl32 = ((wg & 1) << 4) + dl;    // col within the 32-wide chunk

    floatx4 accG0 = {0.f, 0.f, 0.f, 0.f}, accG1 = {0.f, 0.f, 0.f, 0.f};

    for (int s = 0; s < T_STEPS; ++s) {
      const int pc = s & 1;
      if (s == 0) {
        // cs-part
#pragma unroll
        for (int ks = 16; ks < 21; ++ks) {
          bf16x8 a = *(const bf16x8*)(cs_bf + row * 160 + (ks - 16) * 32 + q * 8);
          accG0 = mfma_bf16(a, *(const bf16x8*)(b0row + ks * 32 + q * 8), accG0);
          accG1 = mfma_bf16(a, *(const bf16x8*)(b1row + ks * 32 + q * 8), accG1);
        }
        // emb from E row 0
#pragma unroll 4
        for (int ks = 0; ks < 16; ++ks) {
          const float* ep = E + ks * 32 + q * 8;
          bf16x8 a;
#pragma unroll
          for (int i = 0; i < 8; ++i) a[i] = (__bf16)ep[i];
          accG0 = mfma_bf16(a, *(const bf16x8*)(b0row + ks * 32 + q * 8), accG0);
          accG1 = mfma_bf16(a, *(const bf16x8*)(b1row + ks * 32 + q * 8), accG1);
        }
      } else {
        // all A-WGs published emb(s-1)?  (one parallel stamp check; acc holds h+cs parts)
        wave_spin(estep, NA, s);
#pragma unroll 8
        for (int ks = 0; ks < 16; ++ks) {
          bf16x8 a = ld_bf8_at(emb_bf + row * 512 + ks * 32 + q * 8);
          accG0 = mfma_bf16(a, *(const bf16x8*)(b0row + ks * 32 + q * 8), accG0);
          accG1 = mfma_bf16(a, *(const bf16x8*)(b1row + ks * 32 + q * 8), accG1);
        }
      }
      // --- exchange z via LDS (wave owns (gate-pair, m-tile)) ---
#pragma unroll
      for (int r = 0; r < 4; ++r) {
        zbuf[(g0w * 32 + mt * 16 + q * 4 + r) * 16 + m16] = accG0[r];
        zbuf[((g0w + 1) * 32 + mt * 16 + q * 4 + r) * 16 + m16] = accG1[r];
      }
      __syncthreads();
      // --- LSTM pointwise; stage h ---
#pragma unroll
      for (int pp = 0; pp < 2; ++pp) {
        const int b = (pp * 256 + t) >> 4;
        float zi = zbuf[(0 * 32 + b) * 16 + dl] + bias0;
        float zf = zbuf[(1 * 32 + b) * 16 + dl] + bias1;
        float zg = zbuf[(2 * 32 + b) * 16 + dl] + bias2;
        float zo = zbuf[(3 * 32 + b) * 16 + dl] + bias3;
        float iv = sigmoidf(zi), fv = sigmoidf(zf);
        float gv = tanhf(zg),    ov = sigmoidf(zo);
        c2[pp] = fv * c2[pp] + iv * gv;
        float h = ov * tanhf(c2[pp]);
        astu16(h_bufg + b * 512 + d, f2bf(h));
        astu8(h8 + b * 512 + d, f2fp8(h));
      }
      stamp_publish(hstep + wg, s + 1);   // single-writer slot, no RMW fan-in
      // --- precompute h+cs part of z(s+1) (overlaps vocab logits+PV) ---
      if (s + 1 < T_STEPS) {
        wave_spin(hstep, NA, s + 1);      // all h(s) final
        accG0 = floatx4{0.f, 0.f, 0.f, 0.f};
        accG1 = floatx4{0.f, 0.f, 0.f, 0.f};
#pragma unroll 8
        for (int ks = 21; ks < 37; ++ks) {
          bf16x8 a = ld_bf8_at(h_bufg + row * 512 + (ks - 21) * 32 + q * 8);
          accG0 = mfma_bf16(a, *(const bf16x8*)(b0row + ks * 32 + q * 8), accG0);
          accG1 = mfma_bf16(a, *(const bf16x8*)(b1row + ks * 32 + q * 8), accG1);
        }
#pragma unroll
        for (int ks = 16; ks < 21; ++ks) {
          bf16x8 a = *(const bf16x8*)(cs_bf + row * 160 + (ks - 16) * 32 + q * 8);
          accG0 = mfma_bf16(a, *(const bf16x8*)(b0row + ks * 32 + q * 8), accG0);
          accG1 = mfma_bf16(a, *(const bf16x8*)(b1row + ks * 32 + q * 8), accG1);
        }
      }
      // --- wait for the 14 PV partials covering our d-chunk (parallel stamp check) ---
      wave_spin(pvstep + dc_a * 16, NJC, s + 1);
      // --- reduce 14 jc-partials + Z, normalize, publish emb_bf ---
      float evs[2];
#pragma unroll
      for (int pp = 0; pp < 2; ++pp) {
        const int b = (pp * 256 + t) >> 4;
        float uv = 0.f, Zv = 0.f;
        const float* up = Upart + ((size_t)(dc_a * NJC) * 32 + b) * 32 + dl32;
#pragma unroll
        for (int g = 0; g < NJC; ++g) uv += aldf(up + g * 1024);
#pragma unroll
        for (int g = 0; g < NJC; ++g) Zv += aldf(Zbuf + pc * (NJC * 32) + g * 32 + b);
        float ev = uv / Zv;
        evs[pp] = ev;
        astu16(emb_bf + b * 512 + d, f2bf(ev));
      }
      // zero the Z parity consumed at step s-1 (all readers done: estep>=s observed).
      // Must drain before estep stamp (next writer gated by hstep(s+2) <- estep(s+1)).
      if (s >= 1 && t < NJC) astf(Zbuf + ((s - 1) & 1) * (NJC * 32) + t * 32 + wg, 0.0f);
      stamp_publish(estep + wg, s + 1);
      // --- deferred out stores (pure sink, off the critical chain) ---
#pragma unroll
      for (int pp = 0; pp < 2; ++pp) {
        const int b = (pp * 256 + t) >> 4;
        out[(size_t)b * (64 * 512) + (size_t)(s + 1) * 512 + d] = evs[pp];
      }
    }
  } else {
    // ---------------- vocab WG ----------------
    const int wgv = wg - NA;
    const int jc = wgv >> 4;          // j-chunk (2304 words)
    const int dc = wgv & 15;          // d-chunk (32 cols) this WG reduces in PV
    const long j0 = (long)wgv * 144;  // own 144-word logits slice
    // Ws^T slice -> LDS
    for (int idx = t; idx < 144 * 64; idx += WG_SIZE) {
      int r2 = idx >> 6, grp = idx & 63;
      long v = *(const long*)(Ws8_g + (j0 + r2) * 512 + grp * 8);
      *(long*)(lds_ws + r2 * 512 + ((grp ^ (r2 & 7)) << 3)) = v;
    }
    // E^T slice [32 d][2304 j] -> LDS, rotated by d-row
    for (int idx = t; idx < 32 * 288; idx += WG_SIZE) {
      int dd = idx / 288, g = idx - dd * 288;
      long v = *(const long*)(E8T_g + (size_t)(dc * 32 + dd) * 32768 + (size_t)jc * 2304 + (size_t)g * 8);
      int g2 = g + dd; if (g2 >= 288) g2 -= 288;
      *(long*)(lds_e8ts + dd * 2304 + (g2 << 3)) = v;
    }
    for (int idx = t; idx < (32 * 160) / 8; idx += WG_SIZE) ((long*)lds_e)[idx] = 0;
    __syncthreads();

    for (int s = 0; s < T_STEPS; ++s) {
      wave_spin(hstep, NA, s + 1);      // all h(s) published (parallel stamp check)
      const int pc = s & 1;
      long ah[2][16];
#pragma unroll
      for (int mtl = 0; mtl < 2; ++mtl)
#pragma unroll
        for (int ks = 0; ks < 16; ++ks)
          ah[mtl][ks] = (long)ald64(h8 + (mtl * 16 + m16) * 512 + ks * 32 + q * 8);
      // logits: 9 n-tiles round-robin over waves
      for (int tile = wv; tile < 9; tile += 4) {
        const int jl = tile * 16 + m16;
        const unsigned char* wrow = lds_ws + jl * 512;
        const int sw = jl & 7;
        floatx4 acc[2] = {{0,0,0,0},{0,0,0,0}};
#pragma unroll
        for (int ks = 0; ks < 16; ++ks) {
          int g = ks * 4 + q;
          long bfrag = *(const long*)(wrow + ((g ^ sw) << 3));
          acc[0] = mfma_fp8(ah[0][ks], bfrag, acc[0]);
          acc[1] = mfma_fp8(ah[1][ks], bfrag, acc[1]);
        }
        const long jg = j0 + jl;
        const float bsv = bs[jg < 32000 ? jg : 31999];
        const bool valid = (jg < 32000);
#pragma unroll
        for (int mtl = 0; mtl < 2; ++mtl)
#pragma unroll
          for (int r = 0; r < 4; ++r) {
            float e = valid ? __expf(acc[mtl][r] + bsv) : 0.0f;
            lds_e[(mtl * 16 + q * 4 + r) * 160 + jl] = f2fp8(e);
          }
      }
      __syncthreads();
      // publish e slice to global (coalesced 4B dwords)
      for (int idx = t; idx < 32 * 36; idx += WG_SIZE) {
        int b = idx / 36, g = idx - b * 36;
        unsigned int v = *(const unsigned int*)(lds_e + b * 160 + g * 4);
        astu32((unsigned int*)(e8g + (size_t)b * 32768 + j0 + g * 4), v);
      }
      // Z partial from the SAME fp8-rounded e (wave 3, lanes 0..31); drained by qstep stamp
      if (t >= 192 && t < 224) {
        const int b = t - 192;
        const unsigned int* rowp = (const unsigned int*)(lds_e + b * 160);
        float z = 0.f;
        for (int g = 0; g < 36; ++g) {
          int w4 = (int)rowp[g];
          z += __builtin_amdgcn_cvt_f32_fp8(w4, 0) + __builtin_amdgcn_cvt_f32_fp8(w4, 1)
             + __builtin_amdgcn_cvt_f32_fp8(w4, 2) + __builtin_amdgcn_cvt_f32_fp8(w4, 3);
        }
        afaddf(Zbuf + pc * (NJC * 32) + jc * 32 + b, z);
      }
      stamp_publish(qstep + wgv, s + 1);
      // group readiness: 16 producers of chunk jc (parallel stamp check)
      wave_spin(qstep + jc * 16, 16, s + 1);
      // --- PV: full partial e[:, jc-chunk] @ E[jc-chunk, dc*32..+32] ---
      {
        const int mtp = wv & 1, ntl = wv >> 1;
        const int dl_local = ntl * 16 + m16;
        const unsigned char* erow = lds_e8ts + dl_local * 2304;
        const unsigned char* arow = e8g + (size_t)(mtp * 16 + m16) * 32768 + (size_t)jc * 2304;
        floatx4 acc0 = {0,0,0,0}, acc1 = {0,0,0,0};
#pragma unroll 8
        for (int ks = 0; ks < 72; ks += 2) {
          long a0 = (long)ald64(arow + ks * 32 + q * 8);
          long a1 = (long)ald64(arow + (ks + 1) * 32 + q * 8);
          int g0i = ks * 4 + q + dl_local; if (g0i >= 288) g0i -= 288;
          int g1i = g0i + 4;               if (g1i >= 288) g1i -= 288;
          acc0 = mfma_fp8(a0, *(const long*)(erow + (g0i << 3)), acc0);
          acc1 = mfma_fp8(a1, *(const long*)(erow + (g1i << 3)), acc1);
        }
        floatx4 accs = acc0 + acc1;
#pragma unroll
        for (int r = 0; r < 4; ++r)
          astf(Upart + ((size_t)(dc * NJC + jc) * 32 + (mtp * 16 + (q << 2) + r)) * 32 + dl_local, accs[r]);
      }
      stamp_publish(pvstep + dc * 16 + jc, s + 1);
    }
  }
}

// ---------------- host ----------------
extern "C" void kernel_launch(void* const* d_in, const int* in_sizes, int n_in,
                              void* d_out, int out_size, void* d_ws, size_t ws_size,
                              hipStream_t stream) {
  const float* content = (const float*)d_in[0];
  const float* style   = (const float*)d_in[1];
  const float* E       = (const float*)d_in[2];
  const float* Wk      = (const float*)d_in[3];
  const float* Wr      = (const float*)d_in[4];
  const float* bvec    = (const float*)d_in[5];
  const float* Ws      = (const float*)d_in[6];
  const float* bs      = (const float*)d_in[7];
  float* out = (float*)d_out;
  char* ws = (char*)d_ws;

  constexpr size_t SZ_WS8  = 32256ull * 512;             // 16,515,072
  constexpr size_t SZ_E8T  = 512ull * 32768;             // 16,777,216
  constexpr size_t SZ_WKRT = 2048ull * 1184 * 2;         //  4,849,664
  constexpr size_t SZ_CS   = 32ull * 160 * 2;            //     10,240
  constexpr size_t SZ_HB   = 32ull * 512 * 2;            //     32,768
  constexpr size_t SZ_H8   = 32ull * 512;                //     16,384
  constexpr size_t SZ_EMB  = 32ull * 512 * 2;            //     32,768
  constexpr size_t SZ_E8G  = 32ull * 32768;              //  1,048,576
  constexpr size_t SZ_UP   = 16ull * 14 * 32 * 32 * 4;   //    917,504
  constexpr size_t SZ_ZB   = 2ull * NJC * 32 * 4;        //      3,584
  constexpr size_t SZ_HS   = 64ull * 4;                  //        256 (32 used)
  constexpr size_t SZ_ES   = 64ull * 4;                  //        256 (32 used)
  constexpr size_t SZ_QS   = 256ull * 4;                 //      1,024 (224 used)
  constexpr size_t SZ_PS   = 256ull * 4;                 //      1,024 (16*14 used)

  constexpr size_t OFF_WS8  = 0;
  constexpr size_t OFF_E8T  = OFF_WS8 + SZ_WS8;
  constexpr size_t OFF_WKRT = OFF_E8T + SZ_E8T;
  constexpr size_t OFF_CS   = OFF_WKRT + SZ_WKRT;
  constexpr size_t OFF_HB   = OFF_CS + SZ_CS;
  constexpr size_t OFF_H8   = OFF_HB + SZ_HB;
  constexpr size_t OFF_EMB  = OFF_H8 + SZ_H8;
  constexpr size_t OFF_E8G  = OFF_EMB + SZ_EMB;
  constexpr size_t OFF_UP   = OFF_E8G + SZ_E8G;
  constexpr size_t OFF_ZB   = OFF_UP + SZ_UP;
  constexpr size_t OFF_HS   = OFF_ZB + SZ_ZB;
  constexpr size_t OFF_ES   = OFF_HS + SZ_HS;
  constexpr size_t OFF_QS   = OFF_ES + SZ_ES;
  constexpr size_t OFF_PS   = OFF_QS + SZ_QS;

  unsigned char*  Ws8_g = (unsigned char*)(ws + OFF_WS8);
  unsigned char*  E8T_g = (unsigned char*)(ws + OFF_E8T);
  unsigned short* WkrT  = (unsigned short*)(ws + OFF_WKRT);
  unsigned short* cs_bf = (unsigned short*)(ws + OFF_CS);
  unsigned short* h_bufg= (unsigned short*)(ws + OFF_HB);
  unsigned char*  h8    = (unsigned char*)(ws + OFF_H8);
  unsigned short* emb_bf= (unsigned short*)(ws + OFF_EMB);
  unsigned char*  e8g   = (unsigned char*)(ws + OFF_E8G);
  float* Upart          = (float*)(ws + OFF_UP);
  float* Zbuf           = (float*)(ws + OFF_ZB);
  int* hstep            = (int*)(ws + OFF_HS);
  int* estep            = (int*)(ws + OFF_ES);
  int* qstep            = (int*)(ws + OFF_QS);
  int* pvstep           = (int*)(ws + OFF_PS);

  // zero state (ws poisoned each call)
  hipMemsetAsync(Ws8_g, 0, SZ_WS8, stream);
  hipMemsetAsync(E8T_g, 0, SZ_E8T, stream);
  hipMemsetAsync(WkrT, 0, SZ_WKRT, stream);
  hipMemsetAsync(ws + OFF_ZB, 0, SZ_ZB + SZ_HS + SZ_ES + SZ_QS + SZ_PS, stream);

  // transposed weight copies; Wkr k-layout = Wk(656) | pad16 | Wr(512)
  k_transpose_fp8<<<dim3(8, 500), 256, 0, stream>>>(Ws, Ws8_g, 512, 32000, 512);
  k_transpose_fp8<<<dim3(500, 8), 256, 0, stream>>>(E, E8T_g, 32000, 512, 32768);
  k_transpose<<<dim3(11, 32), 256, 0, stream>>>(Wk, WkrT, 656, 2048, 1184, 0);
  k_transpose<<<dim3(8, 32), 256, 0, stream>>>(Wr, WkrT, 512, 2048, 1184, 672);
  k_init<<<64, 256, 0, stream>>>(content, style, E, cs_bf, out);

  void* args[] = { (void*)&bvec, (void*)&bs, (void*)&Ws8_g, (void*)&E8T_g, (void*)&WkrT,
                   (void*)&cs_bf, (void*)&E, (void*)&h_bufg, (void*)&h8, (void*)&emb_bf,
                   (void*)&e8g, (void*)&Upart, (void*)&Zbuf,
                   (void*)&hstep, (void*)&estep, (void*)&qstep, (void*)&pvstep,
                   (void*)&out };
  hipLaunchCooperativeKernel((void*)k_main, dim3(NWG), dim3(WG_SIZE), args, 0, stream);

  (void)in_sizes; (void)n_in; (void)out_size; (void)ws_size;
}